// Round 13
// baseline (230.609 us; speedup 1.0000x reference)
//
#include <hip/hip_runtime.h>
#include <math.h>

#define Cdim   256
#define Ssp    8192      // D*H*W
#define Npts   65536
#define NCODES 1024
#define BETA   0.25f
#define MT     64        // points per GEMM block
#define NKC    48        // K-chunks of 16 (K=768 split: [zh|zh|zl] x [eh|el|eh])
#define ESCALE 8192.0f   // keep el out of f16-subnormal truncation
#define WS_NEED (65536 + (size_t)786432 * 2)

typedef _Float16 f16;
typedef f16   half8  __attribute__((ext_vector_type(8)));
typedef float f32x16 __attribute__((ext_vector_type(16)));

#define MFMA16(A, B, C) __builtin_amdgcn_mfma_f32_32x32x16_f16(A, B, C, 0, 0, 0)

// ---------------- embed norms ----------------
__global__ __launch_bounds__(256) void enorm_kernel(const float* __restrict__ embed,
                                                    float* __restrict__ enorm) {
    int j = blockIdx.x * 256 + threadIdx.x;
    if (j >= NCODES) return;
    const float4* row = reinterpret_cast<const float4*>(embed + (size_t)j * Cdim);
    float s = 0.f;
#pragma unroll 8
    for (int c4 = 0; c4 < Cdim / 4; ++c4) {
        float4 v = row[c4];
        s += v.x * v.x + v.y * v.y + v.z * v.z + v.w * v.w;
    }
    enorm[j] = s;
}

// ---------------- prep: split embed into f16 hi/lo, chunk-tiled ----------------
// Bws: [kc=48][code=1024][k'=16] f16. k = kc*16+k'; k 0..255 -> eh, 256..511 -> el,
// 512..767 -> eh. Scaled by ESCALE. (verified rounds 5-12)
__global__ __launch_bounds__(256) void prep_kernel(const float* __restrict__ embed,
                                                   f16* __restrict__ Bws) {
    int tid = blockIdx.x * 256 + threadIdx.x;
    int o4 = tid * 4;
    int kc = o4 >> 14;
    int r  = o4 & 16383;
    int j  = r >> 4;
    int k0 = r & 15;
#pragma unroll
    for (int i = 0; i < 4; ++i) {
        int k = kc * 16 + k0 + i;
        int c = k & 255;
        float ev = embed[j * 256 + c] * ESCALE;
        f16 eh = (f16)ev;
        f16 v  = (k >= 256 && k < 512) ? (f16)(ev - (float)eh) : eh;
        Bws[o4 + i] = v;
    }
}

// granule id (region boundaries 16/32 verified rounds 5-12)
#define GG(k) (((k) < 16) ? (2 * (k) + kb) : ((k) < 32) ? (2 * ((k) - 16) + kb) \
                                                        : (32 + 2 * ((k) - 32) + kb))

// ---------------- MFMA GEMM + fused argmin + loss (v9: counted-vmcnt LDS-B) ----------------
// 512 thr / 8 waves, 64 points x ALL 1024 codes. A = [zh|zl] 64KB LDS (r11 staging
// verbatim). B: 2x32KB LDS double buffer filled by block-wide global_load_lds DMA.
// Per chunk: {6 ds_read -> s_barrier -> DMA(kc+2 -> buf[cur]) -> 8 MFMA ->
// s_waitcnt vmcnt(4) [COUNTED: kc+1 done, kc+2 in flight] -> s_barrier}.
// B LDS swizzle: 16B granule g(j,kb) = (2j+kb) ^ ((j>>2)&7)  (bank-uniform reads);
// DMA source is inverse-swizzled (dest stays linear per global_load_lds rules).
__global__ __launch_bounds__(512, 2) void vq_gemm(const float* __restrict__ z,
                                                  const f16* __restrict__ Bws,
                                                  const float* __restrict__ enorm,
                                                  float* __restrict__ out_idx,
                                                  float* __restrict__ loss_acc,
                                                  float* __restrict__ counts) {
    __shared__ __attribute__((aligned(16))) f16 As[MT * 512];   // 64 KB
    __shared__ __attribute__((aligned(16))) f16 Bt[2][16384];   // 64 KB (2x32KB)
    __shared__ float en_s[NCODES];                              // 4 KB
    __shared__ float znp[256];
    __shared__ float zn_s[MT];
    __shared__ float redv[8 * MT];
    __shared__ int   redi[8 * MT];

    const int t  = threadIdx.x;
    const int l  = t & 63;
    const int w  = t >> 6;            // 0..7 : codes [w*128, +128)
    const int ln = l & 31;
    const int kb = l >> 5;
    const int n0 = blockIdx.x * MT;
    const int b  = n0 >> 13;
    const int s0 = n0 & 8191;

    // ---- DMA source offsets: inverse of g(j,kb) = (2j+kb) ^ ((j>>2)&7) ----
    int srcel[4];
#pragma unroll
    for (int i = 0; i < 4; ++i) {
        const int g   = i * 512 + t;          // dest 16B granule (linear)
        const int m   = (g >> 3) & 7;
        const int lin = g ^ m;
        const int j   = lin >> 1;
        const int kb2 = lin & 1;
        srcel[i] = j * 16 + kb2 * 8;          // f16 offset within a chunk
    }

#define STAGEB(kcn, bufi)                                                          \
    {                                                                              \
        const f16* srcb = Bws + (size_t)(kcn) * 16384;                             \
        _Pragma("unroll")                                                          \
        for (int i = 0; i < 4; ++i) {                                              \
            __builtin_amdgcn_global_load_lds(                                      \
                (const __attribute__((address_space(1))) unsigned int*)(srcb + srcel[i]), \
                (__attribute__((address_space(3))) unsigned int*)&Bt[(bufi)][(size_t)(i * 512 + t) * 8], \
                16, 0, 0);                                                         \
        }                                                                          \
    }

    // ---- prologue: DMA chunks 0 and 1 (drained by the staging __syncthreads) ----
    STAGEB(0, 0)
    STAGEB(1, 1)

    // ---- stage A (r11 verbatim: zh granules 0..31, zl 32..63, g^=(p&7)) ----
    if (t < 256) {
        const int p = t & 63;
        const int q = t >> 6;                 // c-quad, 64 c each
        const float* zb = z + (size_t)b * ((size_t)Cdim * Ssp) + s0;
        float zsq = 0.f;
#pragma unroll
        for (int gi = 0; gi < 8; ++gi) {
            const int c0 = q * 64 + gi * 8;
            half8 hh, ll;
#pragma unroll
            for (int u = 0; u < 8; ++u) {     // c ascending -> zsq order == rounds 2/5-12
                float zv = __builtin_nontemporal_load(zb + (size_t)(c0 + u) * Ssp + p);
                zsq += zv * zv;
                f16 zh = (f16)zv;
                hh[u] = zh;
                ll[u] = (f16)(zv - (float)zh);
            }
            const int g0 = c0 >> 3;           // 0..31
            *(half8*)&As[p * 512 + 8 * (g0 ^ (p & 7))]        = hh;
            *(half8*)&As[p * 512 + 8 * ((32 + g0) ^ (p & 7))] = ll;
        }
        znp[q * 64 + p] = zsq;
    }
    for (int i = t; i < NCODES; i += 512) en_s[i] = enorm[i];
    __syncthreads();   // full drain once: DMA 0/1 + A staging complete
    if (t < MT) zn_s[t] = ((znp[t] + znp[64 + t]) + znp[128 + t]) + znp[192 + t];
    __syncthreads();

    // ---- B read byte-offsets (swizzled), constant across the K-loop ----
    int bboff[4];
#pragma unroll
    for (int nn = 0; nn < 4; ++nn) {
        const int j = w * 128 + nn * 32 + ln;
        const int g = (2 * j + kb) ^ ((j >> 2) & 7);
        bboff[nn] = g * 16;
    }

    // ---- K loop: counted-vmcnt double-buffer pipeline ----
    f32x16 acc[2][4] = {};
#pragma unroll 1
    for (int kc = 0; kc < NKC; ++kc) {
        const int cur = kc & 1;
        const char* bbuf = (const char*)(&Bt[0][0]) + cur * 32768;

        // 1. read current chunk's fragments (A from As, B from buf[cur])
        const int gg  = GG(kc);
        const int gsw = 8 * (gg ^ (ln & 7));
        half8 a0  = *(const half8*)&As[ln * 512 + gsw];
        half8 a1  = *(const half8*)&As[(32 + ln) * 512 + gsw];
        half8 bf0 = *(const half8*)(bbuf + bboff[0]);
        half8 bf1 = *(const half8*)(bbuf + bboff[1]);
        half8 bf2 = *(const half8*)(bbuf + bboff[2]);
        half8 bf3 = *(const half8*)(bbuf + bboff[3]);
        __builtin_amdgcn_sched_barrier(0);

        // 2. all waves' reads of buf[cur] are enqueued -> safe to overwrite
        __builtin_amdgcn_s_barrier();
        __builtin_amdgcn_sched_barrier(0);

        // 3. DMA chunk kc+2 into buf[cur] (clamped dup on tail: target buffer
        //    is never read again, and vmcnt counting stays uniform)
        {
            const int kcn = (kc + 2 < NKC) ? kc + 2 : NKC - 1;
            STAGEB(kcn, cur)
        }
        __builtin_amdgcn_sched_barrier(0);

        // 4. MFMA cluster (compiler inserts the lgkmcnt for a*/bf*)
        __builtin_amdgcn_s_setprio(1);
        acc[0][0] = MFMA16(a0, bf0, acc[0][0]);
        acc[1][0] = MFMA16(a1, bf0, acc[1][0]);
        acc[0][1] = MFMA16(a0, bf1, acc[0][1]);
        acc[1][1] = MFMA16(a1, bf1, acc[1][1]);
        acc[0][2] = MFMA16(a0, bf2, acc[0][2]);
        acc[1][2] = MFMA16(a1, bf2, acc[1][2]);
        acc[0][3] = MFMA16(a0, bf3, acc[0][3]);
        acc[1][3] = MFMA16(a1, bf3, acc[1][3]);
        __builtin_amdgcn_s_setprio(0);
        __builtin_amdgcn_sched_barrier(0);

        // 5. COUNTED wait: oldest 4 (= DMA of kc+1) done; kc+2's 4 stay in flight
        asm volatile("s_waitcnt vmcnt(4)" ::: "memory");
        __builtin_amdgcn_s_barrier();
        __builtin_amdgcn_sched_barrier(0);
    }

    // ---- scores + per-wave argmin. C layout: col=lane&31,
    //      row=(reg&3)+8*(reg>>2)+4*(lane>>5)  (verified rounds 5-12) ----
    {
        const int h = l >> 5;
#pragma unroll
        for (int mm = 0; mm < 2; ++mm) {
#pragma unroll
            for (int rg = 0; rg < 16; ++rg) {
                const int row = mm * 32 + (rg & 3) + 8 * (rg >> 2) + 4 * h;
                const float znv = zn_s[row];
                float bv = 3.0e38f; int bi = 0;
#pragma unroll
                for (int nn = 0; nn < 4; ++nn) {
                    const int col = w * 128 + nn * 32 + ln;
                    float k1 = znv + en_s[col];
                    float sc = k1 - acc[mm][nn][rg] * (2.0f / ESCALE);
                    if (sc < bv) { bv = sc; bi = col; }
                }
#pragma unroll
                for (int off = 1; off < 32; off <<= 1) {
                    float ov = __shfl_xor(bv, off, 64);
                    int   oi = __shfl_xor(bi, off, 64);
                    if (ov < bv || (ov == bv && oi < bi)) { bv = ov; bi = oi; }
                }
                if (ln == 0) {
                    redv[w * MT + row] = bv;
                    redi[w * MT + row] = bi;
                }
            }
        }
    }
    __syncthreads();

    // ---- final argmin (w ascending = col ascending); index/count; loss ----
    if (t < MT) {
        float bv = redv[t]; int bi = redi[t];
#pragma unroll
        for (int s = 1; s < 8; ++s) {
            float ov = redv[s * MT + t]; int oi = redi[s * MT + t];
            if (ov < bv || (ov == bv && oi < bi)) { bv = ov; bi = oi; }
        }
        out_idx[n0 + t] = (float)bi;
        atomicAdd(&counts[bi], 1.0f);
        float lsum = bv;
#pragma unroll
        for (int off = 32; off > 0; off >>= 1) lsum += __shfl_down(lsum, off, 64);
        if ((t & 63) == 0) atomicAdd(loss_acc, lsum);
    }
#undef STAGEB
}

// ---------------- epilogue: z_q gather-write only (no z read, no loss) ----------------
__global__ __launch_bounds__(256) void vq_epi(const float* __restrict__ embed,
                                              const float* __restrict__ out_idx,
                                              float* __restrict__ out_zq) {
    const int n = blockIdx.x * 256 + threadIdx.x;
    const int b = n >> 13, s = n & 8191;
    const int idx = (int)out_idx[n];
    const float4* er = reinterpret_cast<const float4*>(embed + (size_t)idx * Cdim);
    float* oq = out_zq + (size_t)b * ((size_t)Cdim * Ssp) + s;
#pragma unroll 4
    for (int c4 = 0; c4 < Cdim / 4; ++c4) {
        float4 e = er[c4];                   // per-lane gather, L2-hot (embed = 1MB)
        const int c = c4 * 4;
        __builtin_nontemporal_store(e.x, oq + (size_t)(c + 0) * Ssp);
        __builtin_nontemporal_store(e.y, oq + (size_t)(c + 1) * Ssp);
        __builtin_nontemporal_store(e.z, oq + (size_t)(c + 2) * Ssp);
        __builtin_nontemporal_store(e.w, oq + (size_t)(c + 3) * Ssp);
    }
}

// ================= fallback (round-4 verified kernel, used if ws too small) =================
#define PTS 64
#define CT  128
#define KC  32
__global__ __launch_bounds__(256, 2) void vq_main_fb(const float* __restrict__ z,
                                                     const float* __restrict__ embed,
                                                     const float* __restrict__ enorm,
                                                     float* __restrict__ out_zq,
                                                     float* __restrict__ out_idx,
                                                     float* __restrict__ loss_acc,
                                                     float* __restrict__ counts) {
    __shared__ __attribute__((aligned(16))) float smem[Cdim * PTS + KC * CT];
    float* zt = smem;
    float* et = smem + Cdim * PTS;
    const int t  = threadIdx.x;
    const int n0 = blockIdx.x * PTS;
    const int b  = n0 >> 13;
    const int s0 = n0 & 8191;
    const float* zb = z + (size_t)b * Cdim * Ssp + s0;
    {
        const int p4 = (t & 15) * 4, crow = t >> 4;
#pragma unroll
        for (int it = 0; it < 16; ++it) {
            int c = it * 16 + crow;
            float4 v = *reinterpret_cast<const float4*>(zb + (size_t)c * Ssp + p4);
            *reinterpret_cast<float4*>(&zt[c * PTS + p4]) = v;
        }
    }
    __syncthreads();
    {
        const int p = t & 63, qq = t >> 6;
        float sacc = 0.f;
#pragma unroll 8
        for (int c = qq * 64; c < qq * 64 + 64; ++c) { float v = zt[c * PTS + p]; sacc += v * v; }
        et[qq * 64 + p] = sacc;
    }
    __syncthreads();
    const int pg = t & 15, jg = t >> 4;
    const int p0 = pg * 4;
    float zn[4];
#pragma unroll
    for (int i = 0; i < 4; ++i) {
        int p = p0 + i;
        zn[i] = ((et[p] + et[64 + p]) + et[128 + p]) + et[192 + p];
    }
    float bestv[4] = {3.0e38f, 3.0e38f, 3.0e38f, 3.0e38f};
    int   besti[4] = {0, 0, 0, 0};
    const int dj = t >> 3, q = t & 7;
    const int sw_st = (q & 3) << 3;
    for (int jt = 0; jt < NCODES / CT; ++jt) {
        const int J0 = jt * CT;
        float acc[4][8];
#pragma unroll
        for (int i = 0; i < 4; ++i)
#pragma unroll
            for (int m = 0; m < 8; ++m) acc[i][m] = 0.f;
        for (int ks = 0; ks < Cdim / KC; ++ks) {
            const int cc0 = ks * KC;
            __syncthreads();
#pragma unroll
            for (int i = 0; i < 4; ++i) {
                const int jrel = dj + 32 * i;
                const float4 v = *reinterpret_cast<const float4*>(
                    embed + (size_t)(J0 + jrel) * Cdim + cc0 + q * 4);
                const int c0 = q * 4;
                const int jsw = jrel ^ sw_st;
                et[(c0 + 0) * CT + jsw] = v.x;
                et[(c0 + 1) * CT + jsw] = v.y;
                et[(c0 + 2) * CT + jsw] = v.z;
                et[(c0 + 3) * CT + jsw] = v.w;
            }
            __syncthreads();
#pragma unroll 4
            for (int c = 0; c < KC; ++c) {
                const float4 zp = *reinterpret_cast<const float4*>(&zt[(cc0 + c) * PTS + p0]);
                const int jb = (jg * 8) ^ (((c >> 2) & 3) << 3);
                const float4 ea = *reinterpret_cast<const float4*>(&et[c * CT + jb]);
                const float4 eb = *reinterpret_cast<const float4*>(&et[c * CT + jb + 4]);
                const float zc[4] = {zp.x, zp.y, zp.z, zp.w};
                const float ec[8] = {ea.x, ea.y, ea.z, ea.w, eb.x, eb.y, eb.z, eb.w};
#pragma unroll
                for (int i = 0; i < 4; ++i)
#pragma unroll
                    for (int m = 0; m < 8; ++m) acc[i][m] += zc[i] * ec[m];
            }
        }
#pragma unroll
        for (int m = 0; m < 8; ++m) {
            const int cid = J0 + jg * 8 + m;
            const float en = enorm[cid];
#pragma unroll
            for (int i = 0; i < 4; ++i) {
                float k1 = zn[i] + en;
                float sc = k1 - 2.0f * acc[i][m];
                if (sc < bestv[i]) { bestv[i] = sc; besti[i] = cid; }
            }
        }
    }
    __syncthreads();
    float* rv = et; int* ri = (int*)(et + 1024); int* idxf = (int*)(et + 2048);
#pragma unroll
    for (int i = 0; i < 4; ++i) { int p = p0 + i; rv[p * 16 + jg] = bestv[i]; ri[p * 16 + jg] = besti[i]; }
    __syncthreads();
    if (t < PTS) {
        int p = t;
        float bv = rv[p * 16]; int bi = ri[p * 16];
        for (int g = 1; g < 16; ++g) {
            float v = rv[p * 16 + g]; int ii = ri[p * 16 + g];
            if (v < bv || (v == bv && ii < bi)) { bv = v; bi = ii; }
        }
        idxf[p] = bi;
        out_idx[n0 + p] = (float)bi;
        atomicAdd(&counts[bi], 1.0f);
    }
    __syncthreads();
    float lsum = 0.f;
    {
        const int p = t & 63, cbase = t >> 6;
        const int myidx = idxf[p];
        const float4* erow4 = reinterpret_cast<const float4*>(embed + (size_t)myidx * Cdim);
        float* ob = out_zq + (size_t)b * Cdim * Ssp + s0 + p;
#pragma unroll 4
        for (int pass = 0; pass < 16; ++pass) {
            int c = cbase * 64 + pass * 4;
            float4 e = erow4[c >> 2];
            ob[(size_t)(c + 0) * Ssp] = e.x;
            ob[(size_t)(c + 1) * Ssp] = e.y;
            ob[(size_t)(c + 2) * Ssp] = e.z;
            ob[(size_t)(c + 3) * Ssp] = e.w;
            float d0 = zt[(c + 0) * PTS + p] - e.x;
            float d1 = zt[(c + 1) * PTS + p] - e.y;
            float d2 = zt[(c + 2) * PTS + p] - e.z;
            float d3 = zt[(c + 3) * PTS + p] - e.w;
            lsum += d0 * d0 + d1 * d1 + d2 * d2 + d3 * d3;
        }
    }
#pragma unroll
    for (int off = 32; off > 0; off >>= 1) lsum += __shfl_down(lsum, off, 64);
    if ((t & 63) == 0) atomicAdd(loss_acc, lsum);
}

// ---------------- finalize ----------------
__global__ __launch_bounds__(1024) void vq_final(const float* __restrict__ counts,
                                                 const float* __restrict__ loss_acc,
                                                 float* __restrict__ out_loss,
                                                 float* __restrict__ out_perp) {
    __shared__ float red[16];
    int t = threadIdx.x;
    float cnt = counts[t];
    float avg = cnt * (1.0f / (float)Npts);
    float term = avg * logf(avg + 1e-10f);
#pragma unroll
    for (int off = 32; off > 0; off >>= 1) term += __shfl_down(term, off, 64);
    if ((t & 63) == 0) red[t >> 6] = term;
    __syncthreads();
    if (t == 0) {
        float s = 0.f;
        for (int i = 0; i < 16; ++i) s += red[i];
        *out_perp = expf(-s);
        *out_loss = BETA * loss_acc[0] * (1.0f / 16777216.0f);
    }
}

extern "C" void kernel_launch(void* const* d_in, const int* in_sizes, int n_in,
                              void* d_out, int out_size, void* d_ws, size_t ws_size,
                              hipStream_t stream) {
    const float* z     = (const float*)d_in[0];
    const float* embed = (const float*)d_in[1];

    float* ws       = (float*)d_ws;
    float* loss_acc = ws;            // [0]
    float* counts   = ws + 64;       // [1024]
    float* enorm    = ws + 2048;     // [1024]

    float* out_zq   = (float*)d_out;
    float* out_idx  = out_zq + (size_t)Npts * Cdim;
    float* out_loss = out_idx + Npts;
    float* out_perp = out_loss + 1;

    hipMemsetAsync(d_ws, 0, 2048 * sizeof(float), stream);
    enorm_kernel<<<NCODES / 256, 256, 0, stream>>>(embed, enorm);

    if (ws_size >= WS_NEED) {
        f16* Bws = (f16*)((char*)d_ws + 65536);
        prep_kernel<<<768, 256, 0, stream>>>(embed, Bws);
        vq_gemm<<<Npts / MT, 512, 0, stream>>>(z, Bws, enorm, out_idx,
                                               loss_acc, counts);
        vq_epi<<<Npts / 256, 256, 0, stream>>>(embed, out_idx, out_zq);
    } else {
        vq_main_fb<<<Npts / PTS, 256, 0, stream>>>(z, embed, enorm, out_zq, out_idx,
                                                   loss_acc, counts);
    }
    vq_final<<<1, 1024, 0, stream>>>(counts, loss_acc, out_loss, out_perp);
}

// Round 14
// 211.142 us; speedup vs baseline: 1.0922x; 1.0922x over previous
//
#include <hip/hip_runtime.h>
#include <math.h>

#define Cdim   256
#define Ssp    8192      // D*H*W
#define Npts   65536
#define NCODES 1024
#define BETA   0.25f
#define MT     64        // points per GEMM block
#define NKC    48        // K-chunks of 16 (K=768 split: [zh|zh|zl] x [eh|el|eh])
#define ESCALE 8192.0f   // keep el out of f16-subnormal truncation
#define WS_NEED (65536 + (size_t)786432 * 2)

typedef _Float16 f16;
typedef f16   half8  __attribute__((ext_vector_type(8)));
typedef float f32x16 __attribute__((ext_vector_type(16)));

#define MFMA16(A, B, C) __builtin_amdgcn_mfma_f32_32x32x16_f16(A, B, C, 0, 0, 0)

// ---------------- embed norms ----------------
__global__ __launch_bounds__(256) void enorm_kernel(const float* __restrict__ embed,
                                                    float* __restrict__ enorm) {
    int j = blockIdx.x * 256 + threadIdx.x;
    if (j >= NCODES) return;
    const float4* row = reinterpret_cast<const float4*>(embed + (size_t)j * Cdim);
    float s = 0.f;
#pragma unroll 8
    for (int c4 = 0; c4 < Cdim / 4; ++c4) {
        float4 v = row[c4];
        s += v.x * v.x + v.y * v.y + v.z * v.z + v.w * v.w;
    }
    enorm[j] = s;
}

// ---------------- prep: split embed into f16 hi/lo, chunk-tiled ----------------
// Bws: [kc=48][code=1024][k'=16] f16. k = kc*16+k'; k 0..255 -> eh, 256..511 -> el,
// 512..767 -> eh. Scaled by ESCALE. (verified rounds 5-13)
__global__ __launch_bounds__(256) void prep_kernel(const float* __restrict__ embed,
                                                   f16* __restrict__ Bws) {
    int tid = blockIdx.x * 256 + threadIdx.x;
    int o4 = tid * 4;
    int kc = o4 >> 14;
    int r  = o4 & 16383;
    int j  = r >> 4;
    int k0 = r & 15;
#pragma unroll
    for (int i = 0; i < 4; ++i) {
        int k = kc * 16 + k0 + i;
        int c = k & 255;
        float ev = embed[j * 256 + c] * ESCALE;
        f16 eh = (f16)ev;
        f16 v  = (k >= 256 && k < 512) ? (f16)(ev - (float)eh) : eh;
        Bws[o4 + i] = v;
    }
}

// granule id (region boundaries 16/32 verified rounds 5-13)
#define GG(k) (((k) < 16) ? (2 * (k) + kb) : ((k) < 32) ? (2 * ((k) - 16) + kb) \
                                                        : (32 + 2 * ((k) - 32) + kb))

// ---------------- MFMA GEMM + fused argmin + loss (v10: small-acc / high-TLP) ----------------
// 512 thr / 8 waves (2wm x 4wn), MT=64 points, 4 jh-passes of 256 codes.
// Per wave: acc = 1 m-frag x 2 n-frags = 32 VGPRs -> total ~100 regs <= 128 cap
// (__launch_bounds__(512,4)) -> 16 waves/CU = 4 waves/SIMD: 2x the TLP of r6-r13.
// That TLP is the latency cover the register pipelines (r8/r12) couldn't provide.
// A = [zh|zl] 64KB LDS; B global->reg with 2-deep prefetch (3 rotating buffers);
// wm-pair waves load identical B addresses (L1 dedupe -> L2 traffic unchanged).
__global__ __launch_bounds__(512, 4) void vq_gemm(const float* __restrict__ z,
                                                  const f16* __restrict__ Bws,
                                                  const float* __restrict__ enorm,
                                                  float* __restrict__ out_idx,
                                                  float* __restrict__ loss_acc,
                                                  float* __restrict__ counts) {
    __shared__ __attribute__((aligned(16))) f16 As[MT * 512];   // 64 KB
    __shared__ float en_s[NCODES];                              // 4 KB
    __shared__ float znp[256];                                  // 1 KB
    __shared__ float zn_s[MT];                                  // 256 B
    __shared__ float redv[4 * MT];                              // 1 KB (wn x row)
    __shared__ int   redi[4 * MT];                              // 1 KB

    const int t  = threadIdx.x;
    const int l  = t & 63;
    const int w  = t >> 6;            // 0..7
    const int wm = w >> 2;            // 0..1 : rows [wm*32, +32)
    const int wn = w & 3;             // 0..3 : codes [wn*64, +64) per jh-pass
    const int ln = l & 31;
    const int kb = l >> 5;
    const int n0 = blockIdx.x * MT;
    const int b  = n0 >> 13;
    const int s0 = n0 & 8191;

    // ---- stage A (r13 verbatim: zh granules 0..31, zl 32..63, g^=(p&7)) ----
    if (t < 256) {
        const int p = t & 63;
        const int q = t >> 6;                 // c-quad, 64 c each
        const float* zb = z + (size_t)b * ((size_t)Cdim * Ssp) + s0;
        float zsq = 0.f;
#pragma unroll
        for (int gi = 0; gi < 8; ++gi) {
            const int c0 = q * 64 + gi * 8;
            half8 hh, ll;
#pragma unroll
            for (int u = 0; u < 8; ++u) {     // c ascending -> zsq order == rounds 2/5-13
                float zv = __builtin_nontemporal_load(zb + (size_t)(c0 + u) * Ssp + p);
                zsq += zv * zv;
                f16 zh = (f16)zv;
                hh[u] = zh;
                ll[u] = (f16)(zv - (float)zh);
            }
            const int g0 = c0 >> 3;           // 0..31
            *(half8*)&As[p * 512 + 8 * (g0 ^ (p & 7))]        = hh;
            *(half8*)&As[p * 512 + 8 * ((32 + g0) ^ (p & 7))] = ll;
        }
        znp[q * 64 + p] = zsq;
    }
    for (int i = t; i < NCODES; i += 512) en_s[i] = enorm[i];
    __syncthreads();
    if (t < MT) zn_s[t] = ((znp[t] + znp[64 + t]) + znp[128 + t]) + znp[192 + t];
    __syncthreads();

    const int rowA = wm * 32 + ln;
    const int h    = l >> 5;

    float bestv = 3.0e38f;            // running fold (threads t<64)
    int   besti = 0;

    // one K-chunk body: A ds_read, issue B(kc+2) into (PA,PB), MFMA on (CA,CB)
#define VBODY(kcv, CA, CB, PA, PB)                                       \
    {                                                                    \
        const int ggx  = GG(kcv);                                        \
        const int gswx = 8 * (ggx ^ (ln & 7));                           \
        half8 a0 = *(const half8*)&As[rowA * 512 + gswx];                \
        const int pf = ((kcv) + 2 < NKC) ? (kcv) + 2 : NKC - 1;          \
        const f16* srcx = bbase + (size_t)pf * 16384;                    \
        PA = *(const half8*)(srcx);                                      \
        PB = *(const half8*)(srcx + 512);                                \
        __builtin_amdgcn_sched_barrier(0);                               \
        __builtin_amdgcn_s_setprio(1);                                   \
        acc0 = MFMA16(a0, CA, acc0);                                     \
        acc1 = MFMA16(a0, CB, acc1);                                     \
        __builtin_amdgcn_s_setprio(0);                                   \
        __builtin_amdgcn_sched_barrier(0);                               \
    }

    // ---- 4 code-passes of 256; wave (wm,wn) owns rows [wm*32,+32) x codes
    //      [jh*256+wn*64, +64) ----
#pragma unroll 1
    for (int jh = 0; jh < 4; ++jh) {
        f32x16 acc0 = {}, acc1 = {};
        const f16* bbase = Bws + (size_t)(jh * 256 + wn * 64 + ln) * 16 + kb * 8;

        // prologue: chunk 0 -> B0, chunk 1 -> B1
        half8 B0a = *(const half8*)(bbase);
        half8 B0b = *(const half8*)(bbase + 512);
        half8 B1a = *(const half8*)(bbase + 16384);
        half8 B1b = *(const half8*)(bbase + 16384 + 512);
        half8 B2a, B2b;

#pragma unroll 1
        for (int kc = 0; kc < NKC; kc += 3) {
            VBODY(kc + 0, B0a, B0b, B2a, B2b)
            VBODY(kc + 1, B1a, B1b, B0a, B0b)
            VBODY(kc + 2, B2a, B2b, B1a, B1b)
        }

        // ---- scores + within-wave argmin. C layout: col=lane&31,
        //      row=(reg&3)+8*(reg>>2)+4*(lane>>5)  (verified rounds 5-13) ----
#pragma unroll
        for (int rg = 0; rg < 16; ++rg) {
            const int row = wm * 32 + (rg & 3) + 8 * (rg >> 2) + 4 * h;
            const float znv = zn_s[row];
            float bv; int bi;
            {
                const int col0 = jh * 256 + wn * 64 + ln;
                float k1 = znv + en_s[col0];
                bv = k1 - acc0[rg] * (2.0f / ESCALE);
                bi = col0;
                const int col1 = col0 + 32;
                k1 = znv + en_s[col1];
                float sc = k1 - acc1[rg] * (2.0f / ESCALE);
                if (sc < bv) { bv = sc; bi = col1; }
            }
#pragma unroll
            for (int off = 1; off < 32; off <<= 1) {
                float ov = __shfl_xor(bv, off, 64);
                int   oi = __shfl_xor(bi, off, 64);
                if (ov < bv || (ov == bv && oi < bi)) { bv = ov; bi = oi; }
            }
            if (ln == 0) {
                redv[wn * MT + row] = bv;
                redi[wn * MT + row] = bi;
            }
        }
        __syncthreads();
        // fold this jh-pass (wn ascending = col ascending; jh outer ascending)
        if (t < MT) {
#pragma unroll
            for (int s = 0; s < 4; ++s) {
                float ov = redv[s * MT + t]; int oi = redi[s * MT + t];
                if (ov < bestv || (ov == bestv && oi < besti)) { bestv = ov; besti = oi; }
            }
        }
        __syncthreads();
    }
#undef VBODY

    // ---- index/count; loss = sum of best scores ----
    if (t < MT) {
        out_idx[n0 + t] = (float)besti;
        atomicAdd(&counts[besti], 1.0f);
        float lsum = bestv;
#pragma unroll
        for (int off = 32; off > 0; off >>= 1) lsum += __shfl_down(lsum, off, 64);
        if (t == 0) atomicAdd(loss_acc, lsum);
    }
}

// ---------------- epilogue: z_q gather-write only (no z read, no loss) ----------------
__global__ __launch_bounds__(256) void vq_epi(const float* __restrict__ embed,
                                              const float* __restrict__ out_idx,
                                              float* __restrict__ out_zq) {
    const int n = blockIdx.x * 256 + threadIdx.x;
    const int b = n >> 13, s = n & 8191;
    const int idx = (int)out_idx[n];
    const float4* er = reinterpret_cast<const float4*>(embed + (size_t)idx * Cdim);
    float* oq = out_zq + (size_t)b * ((size_t)Cdim * Ssp) + s;
#pragma unroll 4
    for (int c4 = 0; c4 < Cdim / 4; ++c4) {
        float4 e = er[c4];                   // per-lane gather, L2-hot (embed = 1MB)
        const int c = c4 * 4;
        __builtin_nontemporal_store(e.x, oq + (size_t)(c + 0) * Ssp);
        __builtin_nontemporal_store(e.y, oq + (size_t)(c + 1) * Ssp);
        __builtin_nontemporal_store(e.z, oq + (size_t)(c + 2) * Ssp);
        __builtin_nontemporal_store(e.w, oq + (size_t)(c + 3) * Ssp);
    }
}

// ================= fallback (round-4 verified kernel, used if ws too small) =================
#define PTS 64
#define CT  128
#define KC  32
__global__ __launch_bounds__(256, 2) void vq_main_fb(const float* __restrict__ z,
                                                     const float* __restrict__ embed,
                                                     const float* __restrict__ enorm,
                                                     float* __restrict__ out_zq,
                                                     float* __restrict__ out_idx,
                                                     float* __restrict__ loss_acc,
                                                     float* __restrict__ counts) {
    __shared__ __attribute__((aligned(16))) float smem[Cdim * PTS + KC * CT];
    float* zt = smem;
    float* et = smem + Cdim * PTS;
    const int t  = threadIdx.x;
    const int n0 = blockIdx.x * PTS;
    const int b  = n0 >> 13;
    const int s0 = n0 & 8191;
    const float* zb = z + (size_t)b * Cdim * Ssp + s0;
    {
        const int p4 = (t & 15) * 4, crow = t >> 4;
#pragma unroll
        for (int it = 0; it < 16; ++it) {
            int c = it * 16 + crow;
            float4 v = *reinterpret_cast<const float4*>(zb + (size_t)c * Ssp + p4);
            *reinterpret_cast<float4*>(&zt[c * PTS + p4]) = v;
        }
    }
    __syncthreads();
    {
        const int p = t & 63, qq = t >> 6;
        float sacc = 0.f;
#pragma unroll 8
        for (int c = qq * 64; c < qq * 64 + 64; ++c) { float v = zt[c * PTS + p]; sacc += v * v; }
        et[qq * 64 + p] = sacc;
    }
    __syncthreads();
    const int pg = t & 15, jg = t >> 4;
    const int p0 = pg * 4;
    float zn[4];
#pragma unroll
    for (int i = 0; i < 4; ++i) {
        int p = p0 + i;
        zn[i] = ((et[p] + et[64 + p]) + et[128 + p]) + et[192 + p];
    }
    float bestv[4] = {3.0e38f, 3.0e38f, 3.0e38f, 3.0e38f};
    int   besti[4] = {0, 0, 0, 0};
    const int dj = t >> 3, q = t & 7;
    const int sw_st = (q & 3) << 3;
    for (int jt = 0; jt < NCODES / CT; ++jt) {
        const int J0 = jt * CT;
        float acc[4][8];
#pragma unroll
        for (int i = 0; i < 4; ++i)
#pragma unroll
            for (int m = 0; m < 8; ++m) acc[i][m] = 0.f;
        for (int ks = 0; ks < Cdim / KC; ++ks) {
            const int cc0 = ks * KC;
            __syncthreads();
#pragma unroll
            for (int i = 0; i < 4; ++i) {
                const int jrel = dj + 32 * i;
                const float4 v = *reinterpret_cast<const float4*>(
                    embed + (size_t)(J0 + jrel) * Cdim + cc0 + q * 4);
                const int c0 = q * 4;
                const int jsw = jrel ^ sw_st;
                et[(c0 + 0) * CT + jsw] = v.x;
                et[(c0 + 1) * CT + jsw] = v.y;
                et[(c0 + 2) * CT + jsw] = v.z;
                et[(c0 + 3) * CT + jsw] = v.w;
            }
            __syncthreads();
#pragma unroll 4
            for (int c = 0; c < KC; ++c) {
                const float4 zp = *reinterpret_cast<const float4*>(&zt[(cc0 + c) * PTS + p0]);
                const int jb = (jg * 8) ^ (((c >> 2) & 3) << 3);
                const float4 ea = *reinterpret_cast<const float4*>(&et[c * CT + jb]);
                const float4 eb = *reinterpret_cast<const float4*>(&et[c * CT + jb + 4]);
                const float zc[4] = {zp.x, zp.y, zp.z, zp.w};
                const float ec[8] = {ea.x, ea.y, ea.z, ea.w, eb.x, eb.y, eb.z, eb.w};
#pragma unroll
                for (int i = 0; i < 4; ++i)
#pragma unroll
                    for (int m = 0; m < 8; ++m) acc[i][m] += zc[i] * ec[m];
            }
        }
#pragma unroll
        for (int m = 0; m < 8; ++m) {
            const int cid = J0 + jg * 8 + m;
            const float en = enorm[cid];
#pragma unroll
            for (int i = 0; i < 4; ++i) {
                float k1 = zn[i] + en;
                float sc = k1 - 2.0f * acc[i][m];
                if (sc < bestv[i]) { bestv[i] = sc; besti[i] = cid; }
            }
        }
    }
    __syncthreads();
    float* rv = et; int* ri = (int*)(et + 1024); int* idxf = (int*)(et + 2048);
#pragma unroll
    for (int i = 0; i < 4; ++i) { int p = p0 + i; rv[p * 16 + jg] = bestv[i]; ri[p * 16 + jg] = besti[i]; }
    __syncthreads();
    if (t < PTS) {
        int p = t;
        float bv = rv[p * 16]; int bi = ri[p * 16];
        for (int g = 1; g < 16; ++g) {
            float v = rv[p * 16 + g]; int ii = ri[p * 16 + g];
            if (v < bv || (v == bv && ii < bi)) { bv = v; bi = ii; }
        }
        idxf[p] = bi;
        out_idx[n0 + p] = (float)bi;
        atomicAdd(&counts[bi], 1.0f);
    }
    __syncthreads();
    float lsum = 0.f;
    {
        const int p = t & 63, cbase = t >> 6;
        const int myidx = idxf[p];
        const float4* erow4 = reinterpret_cast<const float4*>(embed + (size_t)myidx * Cdim);
        float* ob = out_zq + (size_t)b * Cdim * Ssp + s0 + p;
#pragma unroll 4
        for (int pass = 0; pass < 16; ++pass) {
            int c = cbase * 64 + pass * 4;
            float4 e = erow4[c >> 2];
            ob[(size_t)(c + 0) * Ssp] = e.x;
            ob[(size_t)(c + 1) * Ssp] = e.y;
            ob[(size_t)(c + 2) * Ssp] = e.z;
            ob[(size_t)(c + 3) * Ssp] = e.w;
            float d0 = zt[(c + 0) * PTS + p] - e.x;
            float d1 = zt[(c + 1) * PTS + p] - e.y;
            float d2 = zt[(c + 2) * PTS + p] - e.z;
            float d3 = zt[(c + 3) * PTS + p] - e.w;
            lsum += d0 * d0 + d1 * d1 + d2 * d2 + d3 * d3;
        }
    }
#pragma unroll
    for (int off = 32; off > 0; off >>= 1) lsum += __shfl_down(lsum, off, 64);
    if ((t & 63) == 0) atomicAdd(loss_acc, lsum);
}

// ---------------- finalize ----------------
__global__ __launch_bounds__(1024) void vq_final(const float* __restrict__ counts,
                                                 const float* __restrict__ loss_acc,
                                                 float* __restrict__ out_loss,
                                                 float* __restrict__ out_perp) {
    __shared__ float red[16];
    int t = threadIdx.x;
    float cnt = counts[t];
    float avg = cnt * (1.0f / (float)Npts);
    float term = avg * logf(avg + 1e-10f);
#pragma unroll
    for (int off = 32; off > 0; off >>= 1) term += __shfl_down(term, off, 64);
    if ((t & 63) == 0) red[t >> 6] = term;
    __syncthreads();
    if (t == 0) {
        float s = 0.f;
        for (int i = 0; i < 16; ++i) s += red[i];
        *out_perp = expf(-s);
        *out_loss = BETA * loss_acc[0] * (1.0f / 16777216.0f);
    }
}

extern "C" void kernel_launch(void* const* d_in, const int* in_sizes, int n_in,
                              void* d_out, int out_size, void* d_ws, size_t ws_size,
                              hipStream_t stream) {
    const float* z     = (const float*)d_in[0];
    const float* embed = (const float*)d_in[1];

    float* ws       = (float*)d_ws;
    float* loss_acc = ws;            // [0]
    float* counts   = ws + 64;       // [1024]
    float* enorm    = ws + 2048;     // [1024]

    float* out_zq   = (float*)d_out;
    float* out_idx  = out_zq + (size_t)Npts * Cdim;
    float* out_loss = out_idx + Npts;
    float* out_perp = out_loss + 1;

    hipMemsetAsync(d_ws, 0, 2048 * sizeof(float), stream);
    enorm_kernel<<<NCODES / 256, 256, 0, stream>>>(embed, enorm);

    if (ws_size >= WS_NEED) {
        f16* Bws = (f16*)((char*)d_ws + 65536);
        prep_kernel<<<768, 256, 0, stream>>>(embed, Bws);
        vq_gemm<<<Npts / MT, 512, 0, stream>>>(z, Bws, enorm, out_idx,
                                               loss_acc, counts);
        vq_epi<<<Npts / 256, 256, 0, stream>>>(embed, out_idx, out_zq);
    } else {
        vq_main_fb<<<Npts / PTS, 256, 0, stream>>>(z, embed, enorm, out_zq, out_idx,
                                                   loss_acc, counts);
    }
    vq_final<<<1, 1024, 0, stream>>>(counts, loss_acc, out_loss, out_perp);
}

// Round 15
// 202.938 us; speedup vs baseline: 1.1364x; 1.0404x over previous
//
#include <hip/hip_runtime.h>
#include <math.h>

#define Cdim   256
#define Ssp    8192      // D*H*W
#define Npts   65536
#define NCODES 1024
#define BETA   0.25f
#define MT     128       // points per GEMM block
#define NKC    48        // K-chunks of 16 (K=768 split: [zh|zh|zl] x [eh|el|eh])
#define ESCALE 8192.0f   // keep el out of f16-subnormal truncation
#define WS_NEED (65536 + (size_t)786432 * 2)

typedef _Float16 f16;
typedef f16   half8  __attribute__((ext_vector_type(8)));
typedef float f32x16 __attribute__((ext_vector_type(16)));

#define MFMA16(A, B, C) __builtin_amdgcn_mfma_f32_32x32x16_f16(A, B, C, 0, 0, 0)

// ---------------- embed norms ----------------
__global__ __launch_bounds__(256) void enorm_kernel(const float* __restrict__ embed,
                                                    float* __restrict__ enorm) {
    int j = blockIdx.x * 256 + threadIdx.x;
    if (j >= NCODES) return;
    const float4* row = reinterpret_cast<const float4*>(embed + (size_t)j * Cdim);
    float s = 0.f;
#pragma unroll 8
    for (int c4 = 0; c4 < Cdim / 4; ++c4) {
        float4 v = row[c4];
        s += v.x * v.x + v.y * v.y + v.z * v.z + v.w * v.w;
    }
    enorm[j] = s;
}

// ---------------- prep: split embed into f16 hi/lo, chunk-tiled ----------------
// Bws: [kc=48][code=1024][k'=16] f16. k = kc*16+k'; k 0..255 -> eh, 256..511 -> el,
// 512..767 -> eh. Scaled by ESCALE. (verified rounds 5-14)
__global__ __launch_bounds__(256) void prep_kernel(const float* __restrict__ embed,
                                                   f16* __restrict__ Bws) {
    int tid = blockIdx.x * 256 + threadIdx.x;
    int o4 = tid * 4;
    int kc = o4 >> 14;
    int r  = o4 & 16383;
    int j  = r >> 4;
    int k0 = r & 15;
#pragma unroll
    for (int i = 0; i < 4; ++i) {
        int k = kc * 16 + k0 + i;
        int c = k & 255;
        float ev = embed[j * 256 + c] * ESCALE;
        f16 eh = (f16)ev;
        f16 v  = (k >= 256 && k < 512) ? (f16)(ev - (float)eh) : eh;
        Bws[o4 + i] = v;
    }
}

// granule id (region boundaries 16/32 verified rounds 5-14)
#define GG(k) (((k) < 16) ? (2 * (k) + kb) : ((k) < 32) ? (2 * ((k) - 16) + kb) \
                                                        : (32 + 2 * ((k) - 32) + kb))

// ---------------- MFMA GEMM + fused argmin + loss (v11: depth-2 pinned pipeline) ----------------
// r12 structure (512 thr / 8 waves = 2m x 4n, MT=128, 2 jh halves, A in 128KB LDS,
// B global->reg) with a depth-2 pinned pipeline: 3 rotating {A,B} register sets,
// loads issued TWO chunks ahead of use, sched_barrier(0) fences pinning each load
// group before each setprio-wrapped 8-MFMA cluster. Issue-to-use distance =
// 2 chunks (~2x256 cyc of MFMA) >= L3 latency, which depth-1 (r12) undershot.
__global__ __launch_bounds__(512, 2) void vq_gemm(const float* __restrict__ z,
                                                  const f16* __restrict__ Bws,
                                                  const float* __restrict__ enorm,
                                                  float* __restrict__ out_idx,
                                                  float* __restrict__ loss_acc,
                                                  float* __restrict__ counts) {
    __shared__ __attribute__((aligned(16))) f16 As[MT * 512];   // 128 KB
    __shared__ float en_s[NCODES];                              // 4 KB
    __shared__ float znp[4 * MT];                               // 2 KB
    __shared__ float zn_s[MT];                                  // 0.5 KB
    __shared__ float redv[8 * MT];                              // 4 KB (jh,wn) x row
    __shared__ int   redi[8 * MT];                              // 4 KB

    const int t  = threadIdx.x;
    const int l  = t & 63;
    const int w  = t >> 6;            // 0..7
    const int wm = w >> 2;            // 0..1 : rows [wm*64, +64)
    const int wn = w & 3;             // 0..3 : codes [wn*128, +128) per half
    const int ln = l & 31;
    const int kb = l >> 5;
    const int n0 = blockIdx.x * MT;
    const int b  = n0 >> 13;
    const int s0 = n0 & 8191;

    // ---- stage A (zh granules 0..31, zl 32..63, swizzle g^=(p&7)) ----
    {
        const int p = t & 127;        // point row
        const int q = t >> 7;         // c-quad, 64 c each (same 64-c tree as r2/r6)
        const float* zb = z + (size_t)b * ((size_t)Cdim * Ssp) + s0;
        float zsq = 0.f;
#pragma unroll
        for (int gi = 0; gi < 8; ++gi) {
            const int c0 = q * 64 + gi * 8;
            half8 hh, ll;
#pragma unroll
            for (int u = 0; u < 8; ++u) {     // c ascending -> zsq order == rounds 2/5-14
                float zv = zb[(size_t)(c0 + u) * Ssp + p];
                zsq += zv * zv;
                f16 zh = (f16)zv;
                hh[u] = zh;
                ll[u] = (f16)(zv - (float)zh);
            }
            const int g0 = c0 >> 3;           // 0..31
            *(half8*)&As[p * 512 + 8 * (g0 ^ (p & 7))]        = hh;
            *(half8*)&As[p * 512 + 8 * ((32 + g0) ^ (p & 7))] = ll;
        }
        znp[q * MT + p] = zsq;
    }
    for (int i = t; i < NCODES; i += 512) en_s[i] = enorm[i];
    __syncthreads();
    if (t < MT)
        zn_s[t] = ((znp[t] + znp[MT + t]) + znp[2 * MT + t]) + znp[3 * MT + t];
    __syncthreads();

    const int rowA = wm * 64 + ln;

    // load group: A frags from LDS + B frags from global for chunk kcv (clamped)
#define LOADG(kcv, A0, A1, B0, B1, B2, B3)                               \
    {                                                                    \
        const int kcl  = ((kcv) < NKC) ? (kcv) : NKC - 1;                \
        const int ggx  = GG(kcl);                                        \
        const int gswx = 8 * (ggx ^ (ln & 7));                           \
        A0 = *(const half8*)&As[rowA * 512 + gswx];                      \
        A1 = *(const half8*)&As[(rowA + 32) * 512 + gswx];               \
        const f16* srcx = bbase + (size_t)kcl * 16384;                   \
        B0 = *(const half8*)(srcx);                                      \
        B1 = *(const half8*)(srcx + 512);                                \
        B2 = *(const half8*)(srcx + 1024);                               \
        B3 = *(const half8*)(srcx + 1536);                               \
    }

#define MFMAG(A0, A1, B0, B1, B2, B3)                                    \
    __builtin_amdgcn_s_setprio(1);                                       \
    acc[0][0] = MFMA16(A0, B0, acc[0][0]);                               \
    acc[1][0] = MFMA16(A1, B0, acc[1][0]);                               \
    acc[0][1] = MFMA16(A0, B1, acc[0][1]);                               \
    acc[1][1] = MFMA16(A1, B1, acc[1][1]);                               \
    acc[0][2] = MFMA16(A0, B2, acc[0][2]);                               \
    acc[1][2] = MFMA16(A1, B2, acc[1][2]);                               \
    acc[0][3] = MFMA16(A0, B3, acc[0][3]);                               \
    acc[1][3] = MFMA16(A1, B3, acc[1][3]);                               \
    __builtin_amdgcn_s_setprio(0);

    // ---- two code-halves of 512; wave (wm,wn) owns rows [wm*64,+64) x codes
    //      [jh*512+wn*128, +128) ----
#pragma unroll 1
    for (int jh = 0; jh < 2; ++jh) {
        f32x16 acc[2][4] = {};
        const f16* bbase = Bws + (size_t)(jh * 512 + wn * 128 + ln) * 16 + kb * 8;

        half8 aA0, aA1, bA0, bA1, bA2, bA3;   // set A: chunks 0,3,6,...
        half8 aB0, aB1, bB0, bB1, bB2, bB3;   // set B: chunks 1,4,7,...
        half8 aC0, aC1, bC0, bC1, bC2, bC3;   // set C: chunks 2,5,8,...
        LOADG(0, aA0, aA1, bA0, bA1, bA2, bA3)
        LOADG(1, aB0, aB1, bB0, bB1, bB2, bB3)

#pragma unroll 1
        for (int kc = 0; kc < NKC; kc += 3) {
            // depth-2: loads for kc+2 issued before MFMAs on kc
            LOADG(kc + 2, aC0, aC1, bC0, bC1, bC2, bC3)
            __builtin_amdgcn_sched_barrier(0);
            MFMAG(aA0, aA1, bA0, bA1, bA2, bA3)
            __builtin_amdgcn_sched_barrier(0);

            LOADG(kc + 3, aA0, aA1, bA0, bA1, bA2, bA3)
            __builtin_amdgcn_sched_barrier(0);
            MFMAG(aB0, aB1, bB0, bB1, bB2, bB3)
            __builtin_amdgcn_sched_barrier(0);

            LOADG(kc + 4, aB0, aB1, bB0, bB1, bB2, bB3)
            __builtin_amdgcn_sched_barrier(0);
            MFMAG(aC0, aC1, bC0, bC1, bC2, bC3)
            __builtin_amdgcn_sched_barrier(0);
        }

        // ---- scores + per-half argmin. C layout: col=lane&31,
        //      row=(reg&3)+8*(reg>>2)+4*(lane>>5)  (verified rounds 5-14) ----
        const int h = l >> 5;
#pragma unroll
        for (int mm = 0; mm < 2; ++mm) {
#pragma unroll
            for (int rg = 0; rg < 16; ++rg) {
                const int row = wm * 64 + mm * 32 + (rg & 3) + 8 * (rg >> 2) + 4 * h;
                const float znv = zn_s[row];
                float bv = 3.0e38f; int bi = 0;
#pragma unroll
                for (int nn = 0; nn < 4; ++nn) {
                    const int col = jh * 512 + wn * 128 + nn * 32 + ln;
                    float k1 = znv + en_s[col];
                    float sc = k1 - acc[mm][nn][rg] * (2.0f / ESCALE);
                    if (sc < bv) { bv = sc; bi = col; }
                }
#pragma unroll
                for (int off = 1; off < 32; off <<= 1) {
                    float ov = __shfl_xor(bv, off, 64);
                    int   oi = __shfl_xor(bi, off, 64);
                    if (ov < bv || (ov == bv && oi < bi)) { bv = ov; bi = oi; }
                }
                if (ln == 0) {
                    redv[(jh * 4 + wn) * MT + row] = bv;
                    redi[(jh * 4 + wn) * MT + row] = bi;
                }
            }
        }
    }
    __syncthreads();

    // ---- final argmin; index/count; loss = sum of best scores ----
    if (t < MT) {
        float bv = redv[t]; int bi = redi[t];
#pragma unroll
        for (int s = 1; s < 8; ++s) {
            float ov = redv[s * MT + t]; int oi = redi[s * MT + t];
            if (ov < bv || (ov == bv && oi < bi)) { bv = ov; bi = oi; }
        }
        out_idx[n0 + t] = (float)bi;
        atomicAdd(&counts[bi], 1.0f);
        float lsum = bv;
#pragma unroll
        for (int off = 32; off > 0; off >>= 1) lsum += __shfl_down(lsum, off, 64);
        if ((t & 63) == 0) atomicAdd(loss_acc, lsum);
    }
#undef LOADG
#undef MFMAG
}

// ---------------- epilogue: z_q gather-write only (no z read, no loss) ----------------
__global__ __launch_bounds__(256) void vq_epi(const float* __restrict__ embed,
                                              const float* __restrict__ out_idx,
                                              float* __restrict__ out_zq) {
    const int n = blockIdx.x * 256 + threadIdx.x;
    const int b = n >> 13, s = n & 8191;
    const int idx = (int)out_idx[n];
    const float4* er = reinterpret_cast<const float4*>(embed + (size_t)idx * Cdim);
    float* oq = out_zq + (size_t)b * ((size_t)Cdim * Ssp) + s;
#pragma unroll 4
    for (int c4 = 0; c4 < Cdim / 4; ++c4) {
        float4 e = er[c4];                   // per-lane gather, L2-hot (embed = 1MB)
        const int c = c4 * 4;
        __builtin_nontemporal_store(e.x, oq + (size_t)(c + 0) * Ssp);
        __builtin_nontemporal_store(e.y, oq + (size_t)(c + 1) * Ssp);
        __builtin_nontemporal_store(e.z, oq + (size_t)(c + 2) * Ssp);
        __builtin_nontemporal_store(e.w, oq + (size_t)(c + 3) * Ssp);
    }
}

// ================= fallback (round-4 verified kernel, used if ws too small) =================
#define PTS 64
#define CT  128
#define KC  32
__global__ __launch_bounds__(256, 2) void vq_main_fb(const float* __restrict__ z,
                                                     const float* __restrict__ embed,
                                                     const float* __restrict__ enorm,
                                                     float* __restrict__ out_zq,
                                                     float* __restrict__ out_idx,
                                                     float* __restrict__ loss_acc,
                                                     float* __restrict__ counts) {
    __shared__ __attribute__((aligned(16))) float smem[Cdim * PTS + KC * CT];
    float* zt = smem;
    float* et = smem + Cdim * PTS;
    const int t  = threadIdx.x;
    const int n0 = blockIdx.x * PTS;
    const int b  = n0 >> 13;
    const int s0 = n0 & 8191;
    const float* zb = z + (size_t)b * Cdim * Ssp + s0;
    {
        const int p4 = (t & 15) * 4, crow = t >> 4;
#pragma unroll
        for (int it = 0; it < 16; ++it) {
            int c = it * 16 + crow;
            float4 v = *reinterpret_cast<const float4*>(zb + (size_t)c * Ssp + p4);
            *reinterpret_cast<float4*>(&zt[c * PTS + p4]) = v;
        }
    }
    __syncthreads();
    {
        const int p = t & 63, qq = t >> 6;
        float sacc = 0.f;
#pragma unroll 8
        for (int c = qq * 64; c < qq * 64 + 64; ++c) { float v = zt[c * PTS + p]; sacc += v * v; }
        et[qq * 64 + p] = sacc;
    }
    __syncthreads();
    const int pg = t & 15, jg = t >> 4;
    const int p0 = pg * 4;
    float zn[4];
#pragma unroll
    for (int i = 0; i < 4; ++i) {
        int p = p0 + i;
        zn[i] = ((et[p] + et[64 + p]) + et[128 + p]) + et[192 + p];
    }
    float bestv[4] = {3.0e38f, 3.0e38f, 3.0e38f, 3.0e38f};
    int   besti[4] = {0, 0, 0, 0};
    const int dj = t >> 3, q = t & 7;
    const int sw_st = (q & 3) << 3;
    for (int jt = 0; jt < NCODES / CT; ++jt) {
        const int J0 = jt * CT;
        float acc[4][8];
#pragma unroll
        for (int i = 0; i < 4; ++i)
#pragma unroll
            for (int m = 0; m < 8; ++m) acc[i][m] = 0.f;
        for (int ks = 0; ks < Cdim / KC; ++ks) {
            const int cc0 = ks * KC;
            __syncthreads();
#pragma unroll
            for (int i = 0; i < 4; ++i) {
                const int jrel = dj + 32 * i;
                const float4 v = *reinterpret_cast<const float4*>(
                    embed + (size_t)(J0 + jrel) * Cdim + cc0 + q * 4);
                const int c0 = q * 4;
                const int jsw = jrel ^ sw_st;
                et[(c0 + 0) * CT + jsw] = v.x;
                et[(c0 + 1) * CT + jsw] = v.y;
                et[(c0 + 2) * CT + jsw] = v.z;
                et[(c0 + 3) * CT + jsw] = v.w;
            }
            __syncthreads();
#pragma unroll 4
            for (int c = 0; c < KC; ++c) {
                const float4 zp = *reinterpret_cast<const float4*>(&zt[(cc0 + c) * PTS + p0]);
                const int jb = (jg * 8) ^ (((c >> 2) & 3) << 3);
                const float4 ea = *reinterpret_cast<const float4*>(&et[c * CT + jb]);
                const float4 eb = *reinterpret_cast<const float4*>(&et[c * CT + jb + 4]);
                const float zc[4] = {zp.x, zp.y, zp.z, zp.w};
                const float ec[8] = {ea.x, ea.y, ea.z, ea.w, eb.x, eb.y, eb.z, eb.w};
#pragma unroll
                for (int i = 0; i < 4; ++i)
#pragma unroll
                    for (int m = 0; m < 8; ++m) acc[i][m] += zc[i] * ec[m];
            }
        }
#pragma unroll
        for (int m = 0; m < 8; ++m) {
            const int cid = J0 + jg * 8 + m;
            const float en = enorm[cid];
#pragma unroll
            for (int i = 0; i < 4; ++i) {
                float k1 = zn[i] + en;
                float sc = k1 - 2.0f * acc[i][m];
                if (sc < bestv[i]) { bestv[i] = sc; besti[i] = cid; }
            }
        }
    }
    __syncthreads();
    float* rv = et; int* ri = (int*)(et + 1024); int* idxf = (int*)(et + 2048);
#pragma unroll
    for (int i = 0; i < 4; ++i) { int p = p0 + i; rv[p * 16 + jg] = bestv[i]; ri[p * 16 + jg] = besti[i]; }
    __syncthreads();
    if (t < PTS) {
        int p = t;
        float bv = rv[p * 16]; int bi = ri[p * 16];
        for (int g = 1; g < 16; ++g) {
            float v = rv[p * 16 + g]; int ii = ri[p * 16 + g];
            if (v < bv || (v == bv && ii < bi)) { bv = v; bi = ii; }
        }
        idxf[p] = bi;
        out_idx[n0 + p] = (float)bi;
        atomicAdd(&counts[bi], 1.0f);
    }
    __syncthreads();
    float lsum = 0.f;
    {
        const int p = t & 63, cbase = t >> 6;
        const int myidx = idxf[p];
        const float4* erow4 = reinterpret_cast<const float4*>(embed + (size_t)myidx * Cdim);
        float* ob = out_zq + (size_t)b * Cdim * Ssp + s0 + p;
#pragma unroll 4
        for (int pass = 0; pass < 16; ++pass) {
            int c = cbase * 64 + pass * 4;
            float4 e = erow4[c >> 2];
            ob[(size_t)(c + 0) * Ssp] = e.x;
            ob[(size_t)(c + 1) * Ssp] = e.y;
            ob[(size_t)(c + 2) * Ssp] = e.z;
            ob[(size_t)(c + 3) * Ssp] = e.w;
            float d0 = zt[(c + 0) * PTS + p] - e.x;
            float d1 = zt[(c + 1) * PTS + p] - e.y;
            float d2 = zt[(c + 2) * PTS + p] - e.z;
            float d3 = zt[(c + 3) * PTS + p] - e.w;
            lsum += d0 * d0 + d1 * d1 + d2 * d2 + d3 * d3;
        }
    }
#pragma unroll
    for (int off = 32; off > 0; off >>= 1) lsum += __shfl_down(lsum, off, 64);
    if ((t & 63) == 0) atomicAdd(loss_acc, lsum);
}

// ---------------- finalize ----------------
__global__ __launch_bounds__(1024) void vq_final(const float* __restrict__ counts,
                                                 const float* __restrict__ loss_acc,
                                                 float* __restrict__ out_loss,
                                                 float* __restrict__ out_perp) {
    __shared__ float red[16];
    int t = threadIdx.x;
    float cnt = counts[t];
    float avg = cnt * (1.0f / (float)Npts);
    float term = avg * logf(avg + 1e-10f);
#pragma unroll
    for (int off = 32; off > 0; off >>= 1) term += __shfl_down(term, off, 64);
    if ((t & 63) == 0) red[t >> 6] = term;
    __syncthreads();
    if (t == 0) {
        float s = 0.f;
        for (int i = 0; i < 16; ++i) s += red[i];
        *out_perp = expf(-s);
        *out_loss = BETA * loss_acc[0] * (1.0f / 16777216.0f);
    }
}

extern "C" void kernel_launch(void* const* d_in, const int* in_sizes, int n_in,
                              void* d_out, int out_size, void* d_ws, size_t ws_size,
                              hipStream_t stream) {
    const float* z     = (const float*)d_in[0];
    const float* embed = (const float*)d_in[1];

    float* ws       = (float*)d_ws;
    float* loss_acc = ws;            // [0]
    float* counts   = ws + 64;       // [1024]
    float* enorm    = ws + 2048;     // [1024]

    float* out_zq   = (float*)d_out;
    float* out_idx  = out_zq + (size_t)Npts * Cdim;
    float* out_loss = out_idx + Npts;
    float* out_perp = out_loss + 1;

    hipMemsetAsync(d_ws, 0, 2048 * sizeof(float), stream);
    enorm_kernel<<<NCODES / 256, 256, 0, stream>>>(embed, enorm);

    if (ws_size >= WS_NEED) {
        f16* Bws = (f16*)((char*)d_ws + 65536);
        prep_kernel<<<768, 256, 0, stream>>>(embed, Bws);
        vq_gemm<<<Npts / MT, 512, 0, stream>>>(z, Bws, enorm, out_idx,
                                               loss_acc, counts);
        vq_epi<<<Npts / 256, 256, 0, stream>>>(embed, out_idx, out_zq);
    } else {
        vq_main_fb<<<Npts / PTS, 256, 0, stream>>>(z, embed, enorm, out_zq, out_idx,
                                                   loss_acc, counts);
    }
    vq_final<<<1, 1024, 0, stream>>>(counts, loss_acc, out_loss, out_perp);
}

// Round 16
// 197.736 us; speedup vs baseline: 1.1662x; 1.0263x over previous
//
#include <hip/hip_runtime.h>
#include <math.h>

#define Cdim   256
#define Ssp    8192      // D*H*W
#define Npts   65536
#define NCODES 1024
#define BETA   0.25f
#define MT     128       // points per GEMM block
#define ESCALE 8192.0f   // keep el out of f16-subnormal truncation
#define WS_NEED (65536 + (size_t)786432 * 2)

typedef _Float16 f16;
typedef f16   half8  __attribute__((ext_vector_type(8)));
typedef float f32x16 __attribute__((ext_vector_type(16)));

#define MFMA16(A, B, C) __builtin_amdgcn_mfma_f32_32x32x16_f16(A, B, C, 0, 0, 0)

// ---------------- embed norms ----------------
__global__ __launch_bounds__(256) void enorm_kernel(const float* __restrict__ embed,
                                                    float* __restrict__ enorm) {
    int j = blockIdx.x * 256 + threadIdx.x;
    if (j >= NCODES) return;
    const float4* row = reinterpret_cast<const float4*>(embed + (size_t)j * Cdim);
    float s = 0.f;
#pragma unroll 8
    for (int c4 = 0; c4 < Cdim / 4; ++c4) {
        float4 v = row[c4];
        s += v.x * v.x + v.y * v.y + v.z * v.z + v.w * v.w;
    }
    enorm[j] = s;
}

// ---------------- prep: split embed into f16 hi/lo, chunk-tiled ----------------
// Bws: [kc=32][code=1024][k'=16] f16. kc 0..15 -> eh (c = kc*16+k'), kc 16..31 ->
// el (c = (kc-16)*16+k'). Scaled by ESCALE. (eh duplicate region dropped in v12:
// the eh chunks are register-reused for both zh*eh and zl*eh.)
__global__ __launch_bounds__(256) void prep_kernel(const float* __restrict__ embed,
                                                   f16* __restrict__ Bws) {
    int tid = blockIdx.x * 256 + threadIdx.x;   // 512 blocks x 256 thr x 4 elems
    int o4 = tid * 4;
    int kc = o4 >> 14;
    int r  = o4 & 16383;
    int j  = r >> 4;
    int k0 = r & 15;
#pragma unroll
    for (int i = 0; i < 4; ++i) {
        int k = kc * 16 + k0 + i;
        int c = k & 255;
        float ev = embed[j * 256 + c] * ESCALE;
        f16 eh = (f16)ev;
        f16 v  = (k >= 256) ? (f16)(ev - (float)eh) : eh;   // kc>=16 -> el
        Bws[o4 + i] = v;
    }
}

// ---------------- MFMA GEMM + fused argmin + loss (v12: eh-reuse, B=1.0MB) ----------------
// r12 structure (512 thr / 8 waves = 2m x 4n, MT=128, 2 jh halves, A in 128KB LDS,
// B global->reg, pinned ping-pong + setprio). K restructured: per eh-chunk the
// B fragments are REUSED for both zh*eh and zl*eh (16 MFMAs / B-chunk), then an
// el phase does zh*el (8 MFMAs / chunk). B bytes per block: 1.5MB -> 1.0MB and
// B-load instructions per MFMA halve in the eh phase.
__global__ __launch_bounds__(512, 2) void vq_gemm(const float* __restrict__ z,
                                                  const f16* __restrict__ Bws,
                                                  const float* __restrict__ enorm,
                                                  float* __restrict__ out_idx,
                                                  float* __restrict__ loss_acc,
                                                  float* __restrict__ counts) {
    __shared__ __attribute__((aligned(16))) f16 As[MT * 512];   // 128 KB
    __shared__ float en_s[NCODES];                              // 4 KB
    __shared__ float znp[4 * MT];                               // 2 KB
    __shared__ float zn_s[MT];                                  // 0.5 KB
    __shared__ float redv[8 * MT];                              // 4 KB (jh,wn) x row
    __shared__ int   redi[8 * MT];                              // 4 KB

    const int t  = threadIdx.x;
    const int l  = t & 63;
    const int w  = t >> 6;            // 0..7
    const int wm = w >> 2;            // 0..1 : rows [wm*64, +64)
    const int wn = w & 3;             // 0..3 : codes [wn*128, +128) per half
    const int ln = l & 31;
    const int kb = l >> 5;
    const int n0 = blockIdx.x * MT;
    const int b  = n0 >> 13;
    const int s0 = n0 & 8191;

    // ---- stage A (zh granules 0..31, zl 32..63, swizzle g^=(p&7)) ----
    {
        const int p = t & 127;        // point row
        const int q = t >> 7;         // c-quad, 64 c each (same 64-c tree as r2/r6)
        const float* zb = z + (size_t)b * ((size_t)Cdim * Ssp) + s0;
        float zsq = 0.f;
#pragma unroll
        for (int gi = 0; gi < 8; ++gi) {
            const int c0 = q * 64 + gi * 8;
            half8 hh, ll;
#pragma unroll
            for (int u = 0; u < 8; ++u) {     // c ascending -> zsq order == rounds 2/5-15
                float zv = zb[(size_t)(c0 + u) * Ssp + p];
                zsq += zv * zv;
                f16 zh = (f16)zv;
                hh[u] = zh;
                ll[u] = (f16)(zv - (float)zh);
            }
            const int g0 = c0 >> 3;           // 0..31
            *(half8*)&As[p * 512 + 8 * (g0 ^ (p & 7))]        = hh;
            *(half8*)&As[p * 512 + 8 * ((32 + g0) ^ (p & 7))] = ll;
        }
        znp[q * MT + p] = zsq;
    }
    for (int i = t; i < NCODES; i += 512) en_s[i] = enorm[i];
    __syncthreads();
    if (t < MT)
        zn_s[t] = ((znp[t] + znp[MT + t]) + znp[2 * MT + t]) + znp[3 * MT + t];
    __syncthreads();

    const int rowA = wm * 64 + ln;

    // eh load group: zh+zl A frags (4 ds_read) + eh B frags (4 global), chunk kcv<16
#define LOADGE(kcv, H0, H1, L0, L1, B0, B1, B2, B3)                      \
    {                                                                    \
        const int kcl_ = ((kcv) < 16) ? (kcv) : 15;                      \
        const int gz   = 2 * kcl_ + kb;                                  \
        const int gwh  = 8 * (gz ^ (ln & 7));                            \
        const int gwl  = 8 * ((32 + gz) ^ (ln & 7));                     \
        H0 = *(const half8*)&As[rowA * 512 + gwh];                       \
        H1 = *(const half8*)&As[(rowA + 32) * 512 + gwh];                \
        L0 = *(const half8*)&As[rowA * 512 + gwl];                       \
        L1 = *(const half8*)&As[(rowA + 32) * 512 + gwl];                \
        const f16* srcx = bbase + (size_t)kcl_ * 16384;                  \
        B0 = *(const half8*)(srcx);                                      \
        B1 = *(const half8*)(srcx + 512);                                \
        B2 = *(const half8*)(srcx + 1024);                               \
        B3 = *(const half8*)(srcx + 1536);                               \
    }

    // eh MFMA cluster: 16 MFMAs, B reused for zh and zl terms
#define MFMAGE(H0, H1, L0, L1, B0, B1, B2, B3)                           \
    __builtin_amdgcn_s_setprio(1);                                       \
    acc[0][0] = MFMA16(H0, B0, acc[0][0]);                               \
    acc[1][0] = MFMA16(H1, B0, acc[1][0]);                               \
    acc[0][1] = MFMA16(H0, B1, acc[0][1]);                               \
    acc[1][1] = MFMA16(H1, B1, acc[1][1]);                               \
    acc[0][2] = MFMA16(H0, B2, acc[0][2]);                               \
    acc[1][2] = MFMA16(H1, B2, acc[1][2]);                               \
    acc[0][3] = MFMA16(H0, B3, acc[0][3]);                               \
    acc[1][3] = MFMA16(H1, B3, acc[1][3]);                               \
    acc[0][0] = MFMA16(L0, B0, acc[0][0]);                               \
    acc[1][0] = MFMA16(L1, B0, acc[1][0]);                               \
    acc[0][1] = MFMA16(L0, B1, acc[0][1]);                               \
    acc[1][1] = MFMA16(L1, B1, acc[1][1]);                               \
    acc[0][2] = MFMA16(L0, B2, acc[0][2]);                               \
    acc[1][2] = MFMA16(L1, B2, acc[1][2]);                               \
    acc[0][3] = MFMA16(L0, B3, acc[0][3]);                               \
    acc[1][3] = MFMA16(L1, B3, acc[1][3]);                               \
    __builtin_amdgcn_s_setprio(0);

    // el load group: zh A frags + el B frags, chunk 16<=kcv<32
#define LOADGL(kcv, A0, A1, B0, B1, B2, B3)                              \
    {                                                                    \
        const int kcl_ = ((kcv) < 32) ? (kcv) : 31;                      \
        const int gz   = 2 * (kcl_ - 16) + kb;                           \
        const int gwh  = 8 * (gz ^ (ln & 7));                            \
        A0 = *(const half8*)&As[rowA * 512 + gwh];                       \
        A1 = *(const half8*)&As[(rowA + 32) * 512 + gwh];                \
        const f16* srcx = bbase + (size_t)kcl_ * 16384;                  \
        B0 = *(const half8*)(srcx);                                      \
        B1 = *(const half8*)(srcx + 512);                                \
        B2 = *(const half8*)(srcx + 1024);                               \
        B3 = *(const half8*)(srcx + 1536);                               \
    }

#define MFMAGL(A0, A1, B0, B1, B2, B3)                                   \
    __builtin_amdgcn_s_setprio(1);                                       \
    acc[0][0] = MFMA16(A0, B0, acc[0][0]);                               \
    acc[1][0] = MFMA16(A1, B0, acc[1][0]);                               \
    acc[0][1] = MFMA16(A0, B1, acc[0][1]);                               \
    acc[1][1] = MFMA16(A1, B1, acc[1][1]);                               \
    acc[0][2] = MFMA16(A0, B2, acc[0][2]);                               \
    acc[1][2] = MFMA16(A1, B2, acc[1][2]);                               \
    acc[0][3] = MFMA16(A0, B3, acc[0][3]);                               \
    acc[1][3] = MFMA16(A1, B3, acc[1][3]);                               \
    __builtin_amdgcn_s_setprio(0);

#define SB __builtin_amdgcn_sched_barrier(0);

    // ---- two code-halves of 512; wave (wm,wn) owns rows [wm*64,+64) x codes
    //      [jh*512+wn*128, +128) ----
#pragma unroll 1
    for (int jh = 0; jh < 2; ++jh) {
        f32x16 acc[2][4] = {};
        const f16* bbase = Bws + (size_t)(jh * 512 + wn * 128 + ln) * 16 + kb * 8;

        // ===== phase E: eh chunks 0..15, 16 MFMAs each (B reused zh+zl) =====
        {
            half8 hA0, hA1, lA0, lA1, bA0, bA1, bA2, bA3;   // even chunks
            half8 hB0, hB1, lB0, lB1, bB0, bB1, bB2, bB3;   // odd chunks
            LOADGE(0, hA0, hA1, lA0, lA1, bA0, bA1, bA2, bA3)
#pragma unroll 1
            for (int kc = 0; kc < 16; kc += 2) {
                LOADGE(kc + 1, hB0, hB1, lB0, lB1, bB0, bB1, bB2, bB3)
                SB
                MFMAGE(hA0, hA1, lA0, lA1, bA0, bA1, bA2, bA3)
                SB
                LOADGE(kc + 2, hA0, hA1, lA0, lA1, bA0, bA1, bA2, bA3)
                SB
                MFMAGE(hB0, hB1, lB0, lB1, bB0, bB1, bB2, bB3)
                SB
            }
        }
        // ===== phase L: el chunks 16..31, 8 MFMAs each (zh only) =====
        {
            half8 aA0, aA1, bA0, bA1, bA2, bA3;
            half8 aB0, aB1, bB0, bB1, bB2, bB3;
            LOADGL(16, aA0, aA1, bA0, bA1, bA2, bA3)
#pragma unroll 1
            for (int kc = 16; kc < 32; kc += 2) {
                LOADGL(kc + 1, aB0, aB1, bB0, bB1, bB2, bB3)
                SB
                MFMAGL(aA0, aA1, bA0, bA1, bA2, bA3)
                SB
                LOADGL(kc + 2, aA0, aA1, bA0, bA1, bA2, bA3)
                SB
                MFMAGL(aB0, aB1, bB0, bB1, bB2, bB3)
                SB
            }
        }

        // ---- scores + per-half argmin. C layout: col=lane&31,
        //      row=(reg&3)+8*(reg>>2)+4*(lane>>5)  (verified rounds 5-15) ----
        const int h = l >> 5;
#pragma unroll
        for (int mm = 0; mm < 2; ++mm) {
#pragma unroll
            for (int rg = 0; rg < 16; ++rg) {
                const int row = wm * 64 + mm * 32 + (rg & 3) + 8 * (rg >> 2) + 4 * h;
                const float znv = zn_s[row];
                float bv = 3.0e38f; int bi = 0;
#pragma unroll
                for (int nn = 0; nn < 4; ++nn) {
                    const int col = jh * 512 + wn * 128 + nn * 32 + ln;
                    float k1 = znv + en_s[col];
                    float sc = k1 - acc[mm][nn][rg] * (2.0f / ESCALE);
                    if (sc < bv) { bv = sc; bi = col; }
                }
#pragma unroll
                for (int off = 1; off < 32; off <<= 1) {
                    float ov = __shfl_xor(bv, off, 64);
                    int   oi = __shfl_xor(bi, off, 64);
                    if (ov < bv || (ov == bv && oi < bi)) { bv = ov; bi = oi; }
                }
                if (ln == 0) {
                    redv[(jh * 4 + wn) * MT + row] = bv;
                    redi[(jh * 4 + wn) * MT + row] = bi;
                }
            }
        }
    }
    __syncthreads();

    // ---- final argmin; index/count; loss = sum of best scores ----
    if (t < MT) {
        float bv = redv[t]; int bi = redi[t];
#pragma unroll
        for (int s = 1; s < 8; ++s) {
            float ov = redv[s * MT + t]; int oi = redi[s * MT + t];
            if (ov < bv || (ov == bv && oi < bi)) { bv = ov; bi = oi; }
        }
        out_idx[n0 + t] = (float)bi;
        atomicAdd(&counts[bi], 1.0f);
        float lsum = bv;
#pragma unroll
        for (int off = 32; off > 0; off >>= 1) lsum += __shfl_down(lsum, off, 64);
        if ((t & 63) == 0) atomicAdd(loss_acc, lsum);
    }
#undef LOADGE
#undef MFMAGE
#undef LOADGL
#undef MFMAGL
#undef SB
}

// ---------------- epilogue: z_q gather-write only (no z read, no loss) ----------------
__global__ __launch_bounds__(256) void vq_epi(const float* __restrict__ embed,
                                              const float* __restrict__ out_idx,
                                              float* __restrict__ out_zq) {
    const int n = blockIdx.x * 256 + threadIdx.x;
    const int b = n >> 13, s = n & 8191;
    const int idx = (int)out_idx[n];
    const float4* er = reinterpret_cast<const float4*>(embed + (size_t)idx * Cdim);
    float* oq = out_zq + (size_t)b * ((size_t)Cdim * Ssp) + s;
#pragma unroll 4
    for (int c4 = 0; c4 < Cdim / 4; ++c4) {
        float4 e = er[c4];                   // per-lane gather, L2-hot (embed = 1MB)
        const int c = c4 * 4;
        __builtin_nontemporal_store(e.x, oq + (size_t)(c + 0) * Ssp);
        __builtin_nontemporal_store(e.y, oq + (size_t)(c + 1) * Ssp);
        __builtin_nontemporal_store(e.z, oq + (size_t)(c + 2) * Ssp);
        __builtin_nontemporal_store(e.w, oq + (size_t)(c + 3) * Ssp);
    }
}

// ================= fallback (round-4 verified kernel, used if ws too small) =================
#define PTS 64
#define CT  128
#define KC  32
__global__ __launch_bounds__(256, 2) void vq_main_fb(const float* __restrict__ z,
                                                     const float* __restrict__ embed,
                                                     const float* __restrict__ enorm,
                                                     float* __restrict__ out_zq,
                                                     float* __restrict__ out_idx,
                                                     float* __restrict__ loss_acc,
                                                     float* __restrict__ counts) {
    __shared__ __attribute__((aligned(16))) float smem[Cdim * PTS + KC * CT];
    float* zt = smem;
    float* et = smem + Cdim * PTS;
    const int t  = threadIdx.x;
    const int n0 = blockIdx.x * PTS;
    const int b  = n0 >> 13;
    const int s0 = n0 & 8191;
    const float* zb = z + (size_t)b * Cdim * Ssp + s0;
    {
        const int p4 = (t & 15) * 4, crow = t >> 4;
#pragma unroll
        for (int it = 0; it < 16; ++it) {
            int c = it * 16 + crow;
            float4 v = *reinterpret_cast<const float4*>(zb + (size_t)c * Ssp + p4);
            *reinterpret_cast<float4*>(&zt[c * PTS + p4]) = v;
        }
    }
    __syncthreads();
    {
        const int p = t & 63, qq = t >> 6;
        float sacc = 0.f;
#pragma unroll 8
        for (int c = qq * 64; c < qq * 64 + 64; ++c) { float v = zt[c * PTS + p]; sacc += v * v; }
        et[qq * 64 + p] = sacc;
    }
    __syncthreads();
    const int pg = t & 15, jg = t >> 4;
    const int p0 = pg * 4;
    float zn[4];
#pragma unroll
    for (int i = 0; i < 4; ++i) {
        int p = p0 + i;
        zn[i] = ((et[p] + et[64 + p]) + et[128 + p]) + et[192 + p];
    }
    float bestv[4] = {3.0e38f, 3.0e38f, 3.0e38f, 3.0e38f};
    int   besti[4] = {0, 0, 0, 0};
    const int dj = t >> 3, q = t & 7;
    const int sw_st = (q & 3) << 3;
    for (int jt = 0; jt < NCODES / CT; ++jt) {
        const int J0 = jt * CT;
        float acc[4][8];
#pragma unroll
        for (int i = 0; i < 4; ++i)
#pragma unroll
            for (int m = 0; m < 8; ++m) acc[i][m] = 0.f;
        for (int ks = 0; ks < Cdim / KC; ++ks) {
            const int cc0 = ks * KC;
            __syncthreads();
#pragma unroll
            for (int i = 0; i < 4; ++i) {
                const int jrel = dj + 32 * i;
                const float4 v = *reinterpret_cast<const float4*>(
                    embed + (size_t)(J0 + jrel) * Cdim + cc0 + q * 4);
                const int c0 = q * 4;
                const int jsw = jrel ^ sw_st;
                et[(c0 + 0) * CT + jsw] = v.x;
                et[(c0 + 1) * CT + jsw] = v.y;
                et[(c0 + 2) * CT + jsw] = v.z;
                et[(c0 + 3) * CT + jsw] = v.w;
            }
            __syncthreads();
#pragma unroll 4
            for (int c = 0; c < KC; ++c) {
                const float4 zp = *reinterpret_cast<const float4*>(&zt[(cc0 + c) * PTS + p0]);
                const int jb = (jg * 8) ^ (((c >> 2) & 3) << 3);
                const float4 ea = *reinterpret_cast<const float4*>(&et[c * CT + jb]);
                const float4 eb = *reinterpret_cast<const float4*>(&et[c * CT + jb + 4]);
                const float zc[4] = {zp.x, zp.y, zp.z, zp.w};
                const float ec[8] = {ea.x, ea.y, ea.z, ea.w, eb.x, eb.y, eb.z, eb.w};
#pragma unroll
                for (int i = 0; i < 4; ++i)
#pragma unroll
                    for (int m = 0; m < 8; ++m) acc[i][m] += zc[i] * ec[m];
            }
        }
#pragma unroll
        for (int m = 0; m < 8; ++m) {
            const int cid = J0 + jg * 8 + m;
            const float en = enorm[cid];
#pragma unroll
            for (int i = 0; i < 4; ++i) {
                float k1 = zn[i] + en;
                float sc = k1 - 2.0f * acc[i][m];
                if (sc < bestv[i]) { bestv[i] = sc; besti[i] = cid; }
            }
        }
    }
    __syncthreads();
    float* rv = et; int* ri = (int*)(et + 1024); int* idxf = (int*)(et + 2048);
#pragma unroll
    for (int i = 0; i < 4; ++i) { int p = p0 + i; rv[p * 16 + jg] = bestv[i]; ri[p * 16 + jg] = besti[i]; }
    __syncthreads();
    if (t < PTS) {
        int p = t;
        float bv = rv[p * 16]; int bi = ri[p * 16];
        for (int g = 1; g < 16; ++g) {
            float v = rv[p * 16 + g]; int ii = ri[p * 16 + g];
            if (v < bv || (v == bv && ii < bi)) { bv = v; bi = ii; }
        }
        idxf[p] = bi;
        out_idx[n0 + p] = (float)bi;
        atomicAdd(&counts[bi], 1.0f);
    }
    __syncthreads();
    float lsum = 0.f;
    {
        const int p = t & 63, cbase = t >> 6;
        const int myidx = idxf[p];
        const float4* erow4 = reinterpret_cast<const float4*>(embed + (size_t)myidx * Cdim);
        float* ob = out_zq + (size_t)b * Cdim * Ssp + s0 + p;
#pragma unroll 4
        for (int pass = 0; pass < 16; ++pass) {
            int c = cbase * 64 + pass * 4;
            float4 e = erow4[c >> 2];
            ob[(size_t)(c + 0) * Ssp] = e.x;
            ob[(size_t)(c + 1) * Ssp] = e.y;
            ob[(size_t)(c + 2) * Ssp] = e.z;
            ob[(size_t)(c + 3) * Ssp] = e.w;
            float d0 = zt[(c + 0) * PTS + p] - e.x;
            float d1 = zt[(c + 1) * PTS + p] - e.y;
            float d2 = zt[(c + 2) * PTS + p] - e.z;
            float d3 = zt[(c + 3) * PTS + p] - e.w;
            lsum += d0 * d0 + d1 * d1 + d2 * d2 + d3 * d3;
        }
    }
#pragma unroll
    for (int off = 32; off > 0; off >>= 1) lsum += __shfl_down(lsum, off, 64);
    if ((t & 63) == 0) atomicAdd(loss_acc, lsum);
}

// ---------------- finalize ----------------
__global__ __launch_bounds__(1024) void vq_final(const float* __restrict__ counts,
                                                 const float* __restrict__ loss_acc,
                                                 float* __restrict__ out_loss,
                                                 float* __restrict__ out_perp) {
    __shared__ float red[16];
    int t = threadIdx.x;
    float cnt = counts[t];
    float avg = cnt * (1.0f / (float)Npts);
    float term = avg * logf(avg + 1e-10f);
#pragma unroll
    for (int off = 32; off > 0; off >>= 1) term += __shfl_down(term, off, 64);
    if ((t & 63) == 0) red[t >> 6] = term;
    __syncthreads();
    if (t == 0) {
        float s = 0.f;
        for (int i = 0; i < 16; ++i) s += red[i];
        *out_perp = expf(-s);
        *out_loss = BETA * loss_acc[0] * (1.0f / 16777216.0f);
    }
}

extern "C" void kernel_launch(void* const* d_in, const int* in_sizes, int n_in,
                              void* d_out, int out_size, void* d_ws, size_t ws_size,
                              hipStream_t stream) {
    const float* z     = (const float*)d_in[0];
    const float* embed = (const float*)d_in[1];

    float* ws       = (float*)d_ws;
    float* loss_acc = ws;            // [0]
    float* counts   = ws + 64;       // [1024]
    float* enorm    = ws + 2048;     // [1024]

    float* out_zq   = (float*)d_out;
    float* out_idx  = out_zq + (size_t)Npts * Cdim;
    float* out_loss = out_idx + Npts;
    float* out_perp = out_loss + 1;

    hipMemsetAsync(d_ws, 0, 2048 * sizeof(float), stream);
    enorm_kernel<<<NCODES / 256, 256, 0, stream>>>(embed, enorm);

    if (ws_size >= WS_NEED) {
        f16* Bws = (f16*)((char*)d_ws + 65536);
        prep_kernel<<<512, 256, 0, stream>>>(embed, Bws);   // 32 chunks = 1.0 MB
        vq_gemm<<<Npts / MT, 512, 0, stream>>>(z, Bws, enorm, out_idx,
                                               loss_acc, counts);
        vq_epi<<<Npts / 256, 256, 0, stream>>>(embed, out_idx, out_zq);
    } else {
        vq_main_fb<<<Npts / PTS, 256, 0, stream>>>(z, embed, enorm, out_zq, out_idx,
                                                   loss_acc, counts);
    }
    vq_final<<<1, 1024, 0, stream>>>(counts, loss_acc, out_loss, out_perp);
}